// Round 1
// 380.647 us; speedup vs baseline: 1.0798x; 1.0798x over previous
//
#include <hip/hip_runtime.h>
#include <hip/hip_bf16.h>
#include <stdint.h>

#define N 8192
#define D 128
#define JSEG 512                   // sim columns per block
#define JT   16                    // cols per j-iteration
#define ITERS (JSEG / JT)          // 32
#define IW   32                    // i-rows per wave (2 MFMA tiles stacked)
#define GRID_X (N / JSEG)          // 16
#define GRID_Y (N / 128)           // 64 (4 waves x 32 rows = 128 rows/block)
#define NBLOCKS (GRID_X * GRID_Y)  // 1024 partials

typedef __bf16 bf16x8_t __attribute__((ext_vector_type(8)));
typedef __bf16 bf16x2_t __attribute__((ext_vector_type(2)));
typedef float  f32x4_t  __attribute__((ext_vector_type(4)));

// --- Kernel 1: row-normalize embeddings, cast to bf16 into workspace -------
__global__ __launch_bounds__(256) void normalize_k(const float* __restrict__ emb,
                                                   __bf16* __restrict__ xb) {
    const int row  = blockIdx.x * 4 + (threadIdx.x >> 6);
    const int lane = threadIdx.x & 63;
    const float2* src = reinterpret_cast<const float2*>(emb + (size_t)row * D);
    float2 v = src[lane];
    float ss = v.x * v.x + v.y * v.y;
#pragma unroll
    for (int off = 32; off; off >>= 1) ss += __shfl_xor(ss, off);
    const float inv = 1.0f / fmaxf(sqrtf(ss), 1e-8f);
    bf16x2_t o;
    o.x = (__bf16)(v.x * inv);
    o.y = (__bf16)(v.y * inv);
    *reinterpret_cast<bf16x2_t*>(xb + (size_t)row * D + lane * 2) = o;
}

// --- Kernel 2: fused GEMM + MSE partial with SWAPPED MFMA operands ---------
// R5 theory: old layout forced 4 scalar sim loads/thread/tile (C rows were
// 4 different sim rows) and re-fetched 4 KB of xb per 1 KB of sim -> ~31 TB/s
// of L2 demand at full rate, saturating TCC (~34.5 TB/s).
// Swap: acc = mfma(a=X_jrows, b=X_irows).  Verified layout gives thread
// (q,m) -> pred[i0+m][jbase+q*4 .. +3], i.e. one ALIGNED float4 sim load per
// tile. Each wave owns 32 i-rows (two fixed b-frag sets), so each per-tile
// j-frag load feeds TWO tiles: xb L2 traffic per sim byte halves.
// Per wave-tile: 6 VMEM (4 a-frag dwordx4 + 2 sim float4) for 2 KB of sim.
__global__ __launch_bounds__(256, 4) void gemm_loss_k(const __bf16* __restrict__ xb,
                                                      const float* __restrict__ sim,
                                                      float* __restrict__ partials) {
    const int lane = threadIdx.x & 63;
    const int wave = threadIdx.x >> 6;
    const int m = lane & 15;   // i-row within tile (C col); a/b frag row
    const int q = lane >> 4;   // k-quad; C row-quad (j-col quad after swap)
    const int i0 = blockIdx.y * 128 + wave * IW;
    const int j0 = blockIdx.x * JSEG;

    // Fixed B-operand frags: the wave's 32 i-rows (two 16-row sets). 32 VGPR.
    bf16x8_t bA[4], bB[4];
#pragma unroll
    for (int kk = 0; kk < 4; ++kk) {
        bA[kk] = *reinterpret_cast<const bf16x8_t*>(
            xb + (size_t)(i0 + m) * D + kk * 32 + q * 8);
        bB[kk] = *reinterpret_cast<const bf16x8_t*>(
            xb + (size_t)(i0 + 16 + m) * D + kk * 32 + q * 8);
    }

    // Per-thread sim row pointers: row i0+m (and +16), cols j0 + q*4 + jt*16.
    const float* simA = sim + (size_t)(i0 + m) * N + j0 + q * 4;
    const float* simB = simA + (size_t)16 * N;

    bf16x8_t a[2][4];     // ping-pong j-row frags (32 VGPR)
    f32x4_t  svA[2], svB[2];  // ping-pong sim float4s (16 VGPR)

    // ---- prefetch iteration 0 ----
#pragma unroll
    for (int kk = 0; kk < 4; ++kk)
        a[0][kk] = *reinterpret_cast<const bf16x8_t*>(
            xb + (size_t)(j0 + m) * D + kk * 32 + q * 8);
    svA[0] = *reinterpret_cast<const f32x4_t*>(simA);
    svB[0] = *reinterpret_cast<const f32x4_t*>(simB);

    const f32x4_t zero = {0.0f, 0.0f, 0.0f, 0.0f};
    float local = 0.0f;

#pragma unroll 2
    for (int jt = 0; jt < ITERS; ++jt) {
        const int cur = jt & 1, nxt = cur ^ 1;
        // ---- prefetch jt+1 FIRST (stays in flight under the MFMAs) ----
        if (jt + 1 < ITERS) {
            const int j = j0 + (jt + 1) * JT;
#pragma unroll
            for (int kk = 0; kk < 4; ++kk)
                a[nxt][kk] = *reinterpret_cast<const bf16x8_t*>(
                    xb + (size_t)(j + m) * D + kk * 32 + q * 8);
            svA[nxt] = *reinterpret_cast<const f32x4_t*>(simA + (size_t)(jt + 1) * JT);
            svB[nxt] = *reinterpret_cast<const f32x4_t*>(simB + (size_t)(jt + 1) * JT);
        }
        // ---- two 16x16 pred tiles sharing a[cur] ----
        f32x4_t accA = zero, accB = zero;
#pragma unroll
        for (int kk = 0; kk < 4; ++kk) {
            accA = __builtin_amdgcn_mfma_f32_16x16x32_bf16(a[cur][kk], bA[kk], accA, 0, 0, 0);
            accB = __builtin_amdgcn_mfma_f32_16x16x32_bf16(a[cur][kk], bB[kk], accB, 0, 0, 0);
        }
        // ---- fused (pred - sim)^2; acc[r] = pred[i0+m][jbase+q*4+r] ----
#pragma unroll
        for (int r = 0; r < 4; ++r) {
            const float dA = accA[r] - svA[cur][r];
            local = fmaf(dA, dA, local);
            const float dB = accB[r] - svB[cur][r];
            local = fmaf(dB, dB, local);
        }
    }

#pragma unroll
    for (int off = 32; off; off >>= 1) local += __shfl_xor(local, off);
    __shared__ float wsum[4];
    if (lane == 0) wsum[wave] = local;
    __syncthreads();
    if (threadIdx.x == 0) {
        const int bid = blockIdx.y * gridDim.x + blockIdx.x;
        partials[bid] = wsum[0] + wsum[1] + wsum[2] + wsum[3];
    }
}

// --- Kernel 3: reduce 1024 partials, finalize ------------------------------
__global__ __launch_bounds__(256) void finalize_k(const float* __restrict__ partials,
                                                  float* __restrict__ out) {
    float s = 0.0f;
#pragma unroll
    for (int i = 0; i < NBLOCKS / 256; ++i)
        s += partials[i * 256 + threadIdx.x];
#pragma unroll
    for (int off = 32; off; off >>= 1) s += __shfl_xor(s, off);
    __shared__ float wsum[4];
    if ((threadIdx.x & 63) == 0) wsum[threadIdx.x >> 6] = s;
    __syncthreads();
    if (threadIdx.x == 0)
        out[0] = (wsum[0] + wsum[1] + wsum[2] + wsum[3])
                 * (1.0f / ((float)N * (float)N));
}

extern "C" void kernel_launch(void* const* d_in, const int* in_sizes, int n_in,
                              void* d_out, int out_size, void* d_ws, size_t ws_size,
                              hipStream_t stream) {
    const float* emb = (const float*)d_in[0];
    const float* sim = (const float*)d_in[1];
    __bf16* xb = (__bf16*)d_ws;                                   // 2 MB bf16 x
    float* partials = (float*)((char*)d_ws + (size_t)N * D * sizeof(__bf16));

    normalize_k<<<N / 4, 256, 0, stream>>>(emb, xb);
    gemm_loss_k<<<dim3(GRID_X, GRID_Y), 256, 0, stream>>>(xb, sim, partials);
    finalize_k<<<1, 256, 0, stream>>>(partials, (float*)d_out);
}